// Round 5
// baseline (176.022 us; speedup 1.0000x reference)
//
#include <hip/hip_runtime.h>
#include <math.h>

// GAT aggregation: B=8,S=512,N=32,H=256,V=100001
// Two-phase decomposition: z_c = src.aw1 + cand_c.aw2 + b = h[src] + g[cand_c] + b
//  phase 1 (proj): h[v]=emb[v].aw1, g[v]=emb[v].aw2  — coalesced stream of table
//  phase 2 (gat):  scalar z from h/g, one softmax per position across lanes,
//                  weighted gather-accumulate with NO reductions in the loop.

constexpr int H  = 256;
constexpr int NN = 32;        // neighbors
constexpr int C  = NN + 1;    // candidates: self + neighbors
constexpr int PF = 8;         // gather prefetch ring depth
constexpr float SLOPE = 0.2f;
constexpr float NEGV  = -1e9f;

__device__ __forceinline__ float wave_sum(float v) {
#pragma unroll
  for (int off = 32; off > 0; off >>= 1)
    v += __shfl_xor(v, off, 64);
  return v;
}

__device__ __forceinline__ float wave_max(float v) {
#pragma unroll
  for (int off = 32; off > 0; off >>= 1)
    v = fmaxf(v, __shfl_xor(v, off, 64));
  return v;
}

__device__ __forceinline__ float lane_bcast(float v, int lane) {
  return __uint_as_float(__builtin_amdgcn_readlane(__float_as_uint(v), lane));
}

// Phase 1: one wave per vocab row; lane holds 4 consecutive H-elements.
__global__ __launch_bounds__(256, 8) void proj_kernel(
    const float* __restrict__ emb,   // [V,H]
    const float* __restrict__ a_w,   // [2H]
    float* __restrict__ h,           // [V]
    float* __restrict__ g,           // [V]
    int V)
{
  const int row  = (blockIdx.x * blockDim.x + threadIdx.x) >> 6;
  const int lane = threadIdx.x & 63;
  if (row >= V) return;
  const int l4 = lane << 2;
  const float4 e  = *(const float4*)(emb + (size_t)row * H + l4);
  const float4 w1 = *(const float4*)(a_w + l4);
  const float4 w2 = *(const float4*)(a_w + H + l4);
  float p1 = e.x * w1.x + e.y * w1.y + e.z * w1.z + e.w * w1.w;
  float p2 = e.x * w2.x + e.y * w2.y + e.z * w2.z + e.w * w2.w;
  p1 = wave_sum(p1);
  p2 = wave_sum(p2);
  if (lane == 0) { h[row] = p1; g[row] = p2; }
}

// Phase 2: one wave per (b,s) position.
__global__ __launch_bounds__(256, 4) void gat_kernel(
    const int*   __restrict__ node_ids,   // [npos]
    const int*   __restrict__ neighs,     // [npos, NN]
    const int*   __restrict__ mask,       // [npos, NN]
    const float* __restrict__ emb,        // [V, H]
    const float* __restrict__ h,          // [V]
    const float* __restrict__ g,          // [V]
    const float* __restrict__ a_b,        // [1]
    float*       __restrict__ out,        // [npos, H]
    int npos)
{
  const int wid  = (blockIdx.x * blockDim.x + threadIdx.x) >> 6;
  const int lane = threadIdx.x & 63;
  if (wid >= npos) return;
  const int l4 = lane << 2;

  // Lane-parallel: lane 0 = self, lanes 1..32 = neighbors.
  int   my_idx  = 0;
  float my_madd = 0.f;
  if (lane == 0) {
    my_idx = node_ids[wid];
  } else if (lane <= NN) {
    my_idx  = neighs[wid * NN + lane - 1];
    my_madd = mask[wid * NN + lane - 1] ? NEGV : 0.f;
  }

  // Scalar attention logits: z_c = h[src] + g[idx_c] + b  (no dot products!)
  float gv = (lane <= NN) ? g[my_idx] : 0.f;
  float hv = (lane == 0)  ? h[my_idx] : 0.f;
  const float hs = lane_bcast(hv, 0);
  const float z  = hs + gv + a_b[0];
  float a = (z > 0.f) ? z : SLOPE * z;            // LeakyReLU(0.2)
  a += my_madd;                                   // mask (c=0 unmasked)
  if (lane > NN) a = -1e30f;                      // inactive lanes

  // One softmax per position, across lanes.
  const float m  = wave_max(a);
  const float p  = __expf(a - m);                 // lanes>NN -> 0
  const float sm = wave_sum(p);
  const float w  = p * (1.f / sm);                // per-lane weight, lane c = w_c

  // Weighted gather-accumulate: lane owns H-elements [l4, l4+4).
  const float4* __restrict__ embv = (const float4*)emb;  // row = H/4 float4
  auto row_lane = [&](int c) -> float4 {
    const int ic = __builtin_amdgcn_readlane(my_idx, c);   // SGPR row index
    return embv[(size_t)ic * (H / 4) + lane];
  };

  float4 buf[PF];
#pragma unroll
  for (int i = 0; i < PF; ++i) buf[i] = row_lane(i);

  float4 acc = {0.f, 0.f, 0.f, 0.f};
#pragma unroll
  for (int c = 0; c < C; ++c) {
    const float4 cur = buf[c & (PF - 1)];
    if (c + PF < C) buf[c & (PF - 1)] = row_lane(c + PF);
    const float wc = lane_bcast(w, c);
    acc.x += wc * cur.x;
    acc.y += wc * cur.y;
    acc.z += wc * cur.z;
    acc.w += wc * cur.w;
  }
  *(float4*)(out + (size_t)wid * H + l4) = acc;
}

extern "C" void kernel_launch(void* const* d_in, const int* in_sizes, int n_in,
                              void* d_out, int out_size, void* d_ws, size_t ws_size,
                              hipStream_t stream) {
  const int*   node_ids = (const int*)d_in[0];
  const int*   neighs   = (const int*)d_in[1];
  const int*   mask     = (const int*)d_in[2];
  const float* emb      = (const float*)d_in[3];
  const float* a_w      = (const float*)d_in[4];
  const float* a_b      = (const float*)d_in[5];
  float*       out      = (float*)d_out;

  const int npos = in_sizes[0];               // B*S = 4096
  const int V    = in_sizes[3] / H;           // 100001
  const int Vpad = (V + 255) & ~255;          // align g past h

  float* hbuf = (float*)d_ws;
  float* gbuf = hbuf + Vpad;

  // Phase 1: one wave per vocab row.
  {
    const int waves_per_block = 256 / 64;
    const int grid = (V + waves_per_block - 1) / waves_per_block;
    proj_kernel<<<grid, 256, 0, stream>>>(emb, a_w, hbuf, gbuf, V);
  }
  // Phase 2: one wave per position.
  {
    const int waves_per_block = 256 / 64;
    const int grid = (npos + waves_per_block - 1) / waves_per_block;
    gat_kernel<<<grid, 256, 0, stream>>>(node_ids, neighs, mask, emb,
                                         hbuf, gbuf, a_b, out, npos);
  }
}